// Round 1
// baseline (328.033 us; speedup 1.0000x reference)
//
#include <hip/hip_runtime.h>

#define TT 200
#define BB 256
#define DD 128
#define HH 128
#define NG 896  // 7*H

typedef _Float16 half8 __attribute__((ext_vector_type(8)));
typedef _Float16 half2v __attribute__((ext_vector_type(2)));
typedef float float4v __attribute__((ext_vector_type(4)));

__device__ __forceinline__ float fdot2_(half2v a, half2v b, float c) {
#if __has_builtin(__builtin_amdgcn_fdot2)
  return __builtin_amdgcn_fdot2(a, b, c, false);
#else
  return c + (float)a[0] * (float)b[0] + (float)a[1] * (float)b[1];
#endif
}

__device__ __forceinline__ float sigmoidf_(float x) { return 1.f / (1.f + __expf(-x)); }
__device__ __forceinline__ float tanhf_(float x) { return 1.f - 2.f / (__expf(2.f * x) + 1.f); }

// Transpose + f16-cast the two weight matrices: W[k][j] (k<128, j<896) -> WT[j][k]
__global__ __launch_bounds__(256) void wtrans_k(const float* __restrict__ Wx,
    const float* __restrict__ Wh, _Float16* __restrict__ WxT, _Float16* __restrict__ WhT) {
  int idx = blockIdx.x * 256 + threadIdx.x;
  if (idx < DD * NG) {
    int k = idx / NG, j = idx % NG;
    WxT[j * DD + k] = (_Float16)Wx[idx];
  } else if (idx < 2 * DD * NG) {
    int i2 = idx - DD * NG;
    int k = i2 / NG, j = i2 % NG;
    WhT[j * DD + k] = (_Float16)Wh[i2];
  }
}

// xg GEMM: rows r = (t-t0)*BB + b for t in [t0,t1); xg[r][col] = x[b,t,:]@W_x[:,col] + bias[col]
// f16 MFMA 16x16x32, A from global f32 (cvt on the fly), B (W_xT) staged in LDS.
__global__ __launch_bounds__(256, 2) void xg_gemm_k(const float* __restrict__ x,
    const _Float16* __restrict__ WxT, const float* __restrict__ bias,
    _Float16* __restrict__ xg, int t0) {
  int mt = blockIdx.x / 7, nt = blockIdx.x % 7;
  __shared__ _Float16 Bld[128][136];  // +8 halfs pad -> 2-way-max bank aliasing (free)
  int tid = threadIdx.x;
  for (int i = tid; i < 128 * 16; i += 256) {
    int r = i >> 4, c8 = (i & 15) << 3;
    *(half8*)&Bld[r][c8] = *(const half8*)(WxT + (size_t)(nt * 128 + r) * DD + c8);
  }
  __syncthreads();
  int wv = tid >> 6, l = tid & 63, lr = l & 15, lk8 = (l >> 4) << 3;
  float4v acc[2][8];
#pragma unroll
  for (int a = 0; a < 2; ++a)
#pragma unroll
    for (int q = 0; q < 8; ++q) acc[a][q] = (float4v){0.f, 0.f, 0.f, 0.f};
  size_t abase[2];
#pragma unroll
  for (int mf = 0; mf < 2; ++mf) {
    int R = mt * 128 + wv * 32 + mf * 16 + lr;  // chunk row
    int t = t0 + (R >> 8), b = R & 255;
    abase[mf] = ((size_t)b * TT + t) * DD + lk8;
  }
#pragma unroll
  for (int kk = 0; kk < 4; ++kk) {
    half8 af[2];
#pragma unroll
    for (int mf = 0; mf < 2; ++mf) {
      float4v x0 = *(const float4v*)(x + abase[mf] + kk * 32);
      float4v x1 = *(const float4v*)(x + abase[mf] + kk * 32 + 4);
      half8 a;
      a[0] = (_Float16)x0[0]; a[1] = (_Float16)x0[1]; a[2] = (_Float16)x0[2]; a[3] = (_Float16)x0[3];
      a[4] = (_Float16)x1[0]; a[5] = (_Float16)x1[1]; a[6] = (_Float16)x1[2]; a[7] = (_Float16)x1[3];
      af[mf] = a;
    }
#pragma unroll
    for (int nf = 0; nf < 8; ++nf) {
      half8 bv = *(const half8*)&Bld[nf * 16 + lr][kk * 32 + lk8];
      acc[0][nf] = __builtin_amdgcn_mfma_f32_16x16x32_f16(af[0], bv, acc[0][nf], 0, 0, 0);
      acc[1][nf] = __builtin_amdgcn_mfma_f32_16x16x32_f16(af[1], bv, acc[1][nf], 0, 0, 0);
    }
  }
  int r4 = (l >> 4) << 2;
#pragma unroll
  for (int nf = 0; nf < 8; ++nf) {
    int col = nt * 128 + nf * 16 + lr;
    float bv = bias[col];
#pragma unroll
    for (int mf = 0; mf < 2; ++mf) {
      int row = mt * 128 + wv * 32 + mf * 16 + r4;
#pragma unroll
      for (int rr = 0; rr < 4; ++rr) {
        xg[(size_t)(row + rr) * NG + col] = (_Float16)(acc[mf][nf][rr] + bv);
      }
    }
  }
}

// Recurrence: one workgroup per sample b. 896 threads: thread j owns gate column j
// (W_h column in 64 half2 VGPRs). h broadcast via LDS (f16). State on threads 0..127.
__global__ __launch_bounds__(896) void rec_k(const _Float16* __restrict__ xg,
    const float* __restrict__ dur, const int* __restrict__ rep,
    const _Float16* __restrict__ WhT, float* __restrict__ out,
    _Float16* __restrict__ st_h, float* __restrict__ st_c, float* __restrict__ st_cb,
    int t0, int t1) {
  int b = blockIdx.x, j = threadIdx.x;
  int tend = rep[b];
  if (t0 > tend) return;  // uniform per block
  int tstop = min(t1 - 1, tend);
  __shared__ __align__(16) _Float16 hbuf[HH];
  __shared__ float gbuf[NG];
  half8 w8[16];
#pragma unroll
  for (int q = 0; q < 16; ++q) w8[q] = *(const half8*)(WhT + (size_t)j * DD + q * 8);
  float c_s = 0.f, cb_s = 0.f;
  if (j < HH) {
    if (t0 == 0) {
      hbuf[j] = (_Float16)0.f;
    } else {
      hbuf[j] = st_h[b * HH + j];
      c_s = st_c[b * HH + j];
      cb_s = st_cb[b * HH + j];
    }
  }
  __syncthreads();
  int gate = j >> 7;
  const _Float16* xgp = xg + (size_t)b * NG + j;
  const size_t stp = (size_t)BB * NG;
  _Float16 xg_c = xgp[0];
  float dt_c = dur[b * TT + t0];
  const half8* hp = (const half8*)hbuf;
  for (int t = t0; t <= tstop; ++t) {
    int tn = t < tstop ? t + 1 : t;
    _Float16 xg_n = xgp[(size_t)(tn - t0) * stp];  // prefetch next step's xg
    float dt_n = dur[b * TT + tn];
    float sacc[4] = {0.f, 0.f, 0.f, 0.f};
#pragma unroll
    for (int q = 0; q < 16; ++q) {
      half8 hv = hp[q];
      half8 wv = w8[q];
#pragma unroll
      for (int p = 0; p < 4; ++p) {
        half2v ha = {hv[2 * p], hv[2 * p + 1]};
        half2v wa = {wv[2 * p], wv[2 * p + 1]};
        sacc[q & 3] = fdot2_(ha, wa, sacc[q & 3]);
      }
    }
    float g = (float)xg_c + ((sacc[0] + sacc[1]) + (sacc[2] + sacc[3]));
    float act;
    if (gate == 2) act = tanhf_(g);
    else if (gate == 6) act = fmaxf(g, 0.f) + log1pf(__expf(-fabsf(g)));  // softplus
    else act = sigmoidf_(g);
    gbuf[j] = act;
    __syncthreads();
    if (j < HH) {
      float iv = gbuf[j], fv = gbuf[HH + j], zv = gbuf[2 * HH + j], ov = gbuf[3 * HH + j];
      float ibv = gbuf[4 * HH + j], fbv = gbuf[5 * HH + j], dv = gbuf[6 * HH + j];
      float cc = fv * c_s + iv * zv;
      cb_s = fbv * cb_s + ibv * zv;
      float cn = cb_s + (cc - cb_s) * __expf(-dv * dt_c);
      float hn = ov * tanhf_(cn);
      c_s = cn;
      if (t == tend) {
        out[b * HH + j] = hn;
        out[BB * HH + b * HH + j] = cn;
      }
      hbuf[j] = (_Float16)hn;
    }
    __syncthreads();
    xg_c = xg_n;
    dt_c = dt_n;
  }
  if (tstop < tend && j < HH) {  // save state for next chunk
    st_h[b * HH + j] = hbuf[j];
    st_c[b * HH + j] = c_s;
    st_cb[b * HH + j] = cb_s;
  }
}

extern "C" void kernel_launch(void* const* d_in, const int* in_sizes, int n_in,
                              void* d_out, int out_size, void* d_ws, size_t ws_size,
                              hipStream_t stream) {
  const float* x = (const float*)d_in[0];
  const float* dur = (const float*)d_in[1];
  const int* rep = (const int*)d_in[2];
  const float* Wx = (const float*)d_in[3];
  const float* Wh = (const float*)d_in[4];
  const float* bias = (const float*)d_in[5];
  float* out = (float*)d_out;
  char* ws = (char*)d_ws;

  size_t off = 0;
  _Float16* WxT = (_Float16*)(ws + off); off += (size_t)NG * DD * 2;
  _Float16* WhT = (_Float16*)(ws + off); off += (size_t)NG * DD * 2;
  _Float16* st_h = (_Float16*)(ws + off); off += (size_t)BB * HH * 2;
  float* st_c = (float*)(ws + off); off += (size_t)BB * HH * 4;
  float* st_cb = (float*)(ws + off); off += (size_t)BB * HH * 4;
  _Float16* xgbuf = (_Float16*)(ws + off);

  size_t avail = ws_size > off ? ws_size - off : 0;
  size_t perT = (size_t)BB * NG * 2;
  int Tc = (int)(avail / perT);
  if (Tc > TT) Tc = TT;
  if (Tc < 1) Tc = 1;

  hipLaunchKernelGGL(wtrans_k, dim3((2 * DD * NG + 255) / 256), dim3(256), 0, stream,
                     Wx, Wh, WxT, WhT);
  for (int t0 = 0; t0 < TT; t0 += Tc) {
    int t1 = t0 + Tc;
    if (t1 > TT) t1 = TT;
    int mtiles = (t1 - t0) * BB / 128;
    hipLaunchKernelGGL(xg_gemm_k, dim3(mtiles * 7), dim3(256), 0, stream,
                       x, WxT, bias, xgbuf, t0);
    hipLaunchKernelGGL(rec_k, dim3(BB), dim3(NG), 0, stream,
                       xgbuf, dur, rep, WhT, out, st_h, st_c, st_cb, t0, t1);
  }
}